// Round 17
// baseline (141.428 us; speedup 1.0000x reference)
//
#include <hip/hip_runtime.h>
#include <hip/hip_bf16.h>
#include <math.h>

#define DIMD 384
#define NHEADS 6
#define HD 64
#define MLPH 768
#define SEQ 2048
#define NBATCH 4
#define NTOK (NBATCH*SEQ)   // 8192

typedef __hip_bfloat16 bf16;

typedef __attribute__((ext_vector_type(8))) short bf16x8;
typedef __attribute__((ext_vector_type(4))) float f32x4;

#define LOG2E 1.44269504088896340736f
#define SC2F 0.18033688011112042f   // 0.125 * log2(e), folded into Q

static __device__ inline float fexp2(float x) { return __builtin_amdgcn_exp2f(x); }

static __device__ inline f32x4 mfma16(bf16x8 a, bf16x8 b, f32x4 c) {
    return __builtin_amdgcn_mfma_f32_16x16x32_bf16(a, b, c, 0, 0, 0);
}

static __device__ inline unsigned int cvtpk(float lo, float hi) {
    unsigned int r;
    asm("v_cvt_pk_bf16_f32 %0, %1, %2" : "=v"(r) : "v"(lo), "v"(hi));
    return r;
}
static __device__ inline float bflo(unsigned int u) { return __builtin_bit_cast(float, u << 16); }
static __device__ inline float bfhi(unsigned int u) { return __builtin_bit_cast(float, u & 0xffff0000u); }

// async global->LDS, 16B per lane. LDS dest must be wave-linear (base + lane*16).
static __device__ inline void gld16(const void* g, void* l) {
    __builtin_amdgcn_global_load_lds(
        (const __attribute__((address_space(1))) unsigned int*)g,
        (__attribute__((address_space(3))) unsigned int*)l, 16, 0, 0);
}

// XCD-aware swizzle (gridDim.x % 8 == 0)
static __device__ inline int xcd_swz(int wg, int nwg) {
    return (wg & 7) * (nwg >> 3) + (wg >> 3);
}

// ---------------------------------------------------------------- LayerNorm
__global__ __launch_bounds__(256) void ln_k(const float* __restrict__ x,
                                            const float* __restrict__ gm,
                                            const float* __restrict__ bt,
                                            bf16* __restrict__ out) {
    int row = blockIdx.x * 4 + (threadIdx.x >> 6);
    int l = threadIdx.x & 63;
    const float* xr = x + (size_t)row * DIMD;
    float v[6];
#pragma unroll
    for (int j = 0; j < 6; ++j) v[j] = xr[l + 64 * j];
    float s = 0.f, s2 = 0.f;
#pragma unroll
    for (int j = 0; j < 6; ++j) { s += v[j]; s2 += v[j] * v[j]; }
#pragma unroll
    for (int m = 1; m < 64; m <<= 1) { s += __shfl_xor(s, m); s2 += __shfl_xor(s2, m); }
    float mu = s * (1.f / DIMD);
    float var = s2 * (1.f / DIMD) - mu * mu;
    float rs = rsqrtf(var + 1e-5f);
    bf16* orow = out + (size_t)row * DIMD;
#pragma unroll
    for (int j = 0; j < 6; ++j) {
        int i = l + 64 * j;
        orow[i] = __float2bfloat16((v[j] - mu) * rs * gm[i] + bt[i]);
    }
}

// --------------------------------- prep: wtrans x4 + dist table + ln1, fused
__global__ __launch_bounds__(256) void prep_k(const float* __restrict__ w1,
                                              const float* __restrict__ w2,
                                              const float* __restrict__ w3,
                                              const float* __restrict__ w4,
                                              bf16* __restrict__ o1,
                                              bf16* __restrict__ o2,
                                              bf16* __restrict__ o3,
                                              bf16* __restrict__ o4,
                                              const float* __restrict__ pos,
                                              bf16* __restrict__ DP,
                                              const float* __restrict__ x,
                                              const float* __restrict__ g1,
                                              const float* __restrict__ b1,
                                              bf16* __restrict__ xn) {
    __shared__ float shbuf[6144];
    int id = blockIdx.x;
    if (id < 1152) {
        float (*t)[33] = (float(*)[33])shbuf;
        const float* W; bf16* O; int K, N;
        if (id < 432)      { W = w1; O = o1; K = 384; N = 1152; }
        else if (id < 576) { W = w2; O = o2; K = 384; N = 384;  id -= 432; }
        else if (id < 864) { W = w3; O = o3; K = 384; N = 768;  id -= 576; }
        else               { W = w4; O = o4; K = 768; N = 384;  id -= 864; }
        int nbx = N >> 5;
        int nb = (id % nbx) * 32, kb = (id / nbx) * 32;
        int tx = threadIdx.x & 31, ty = threadIdx.x >> 5;
#pragma unroll
        for (int i = 0; i < 4; ++i)
            t[ty + 8 * i][tx] = W[(size_t)(kb + ty + 8 * i) * N + nb + tx];
        __syncthreads();
#pragma unroll
        for (int i = 0; i < 4; ++i)
            O[(size_t)(nb + ty + 8 * i) * K + kb + tx] = __float2bfloat16(t[tx][ty + 8 * i]);
    } else if (id < 1664) {
        int blk = id - 1152;              // (b*32+qt)*4 + w
        int w = blk & 3, qt = (blk >> 2) & 31, b = blk >> 7;
        int l = threadIdx.x & 63, tt = threadIdx.x >> 6;
        int lq = l & 15, g = l >> 4;
        const float* posb = pos + (size_t)b * SEQ * 3;
        for (int i = threadIdx.x; i < 1536; i += 256)
            ((f32x4*)shbuf)[i] = ((const f32x4*)posb)[i];
        __syncthreads();
        int q = qt * 64 + w * 16 + lq;
        float px = shbuf[3 * q], py = shbuf[3 * q + 1], pz = shbuf[3 * q + 2];
        char* base = (char*)DP + (size_t)blk * 65536;
        for (int j = 0; j < 8; ++j) {
            int tt8 = tt * 8 + j;
#pragma unroll
            for (int m = 0; m < 2; ++m) {
                int k0 = tt8 * 64 + 32 * m + 4 * g;
                float a[24];
                *(f32x4*)&a[0]  = *(const f32x4*)&shbuf[3 * k0];
                *(f32x4*)&a[4]  = *(const f32x4*)&shbuf[3 * k0 + 4];
                *(f32x4*)&a[8]  = *(const f32x4*)&shbuf[3 * k0 + 8];
                *(f32x4*)&a[12] = *(const f32x4*)&shbuf[3 * (k0 + 16)];
                *(f32x4*)&a[16] = *(const f32x4*)&shbuf[3 * (k0 + 16) + 4];
                *(f32x4*)&a[20] = *(const f32x4*)&shbuf[3 * (k0 + 16) + 8];
                float o8[8];
#pragma unroll
                for (int r = 0; r < 8; ++r) {
                    float dx = px - a[3 * r], dy = py - a[3 * r + 1], dz = pz - a[3 * r + 2];
                    o8[r] = fexp2(-LOG2E * (dx * dx + dy * dy + dz * dz)) * LOG2E;
                }
                uint4 o;
                o.x = cvtpk(o8[0], o8[1]); o.y = cvtpk(o8[2], o8[3]);
                o.z = cvtpk(o8[4], o8[5]); o.w = cvtpk(o8[6], o8[7]);
                *(uint4*)(base + ((size_t)tt8 * 2 + m) * 1024 + l * 16) = o;
            }
        }
    } else {
        int row = (id - 1664) * 4 + (threadIdx.x >> 6);
        int l = threadIdx.x & 63;
        const float* xr = x + (size_t)row * DIMD;
        float v[6];
#pragma unroll
        for (int j = 0; j < 6; ++j) v[j] = xr[l + 64 * j];
        float s = 0.f, s2 = 0.f;
#pragma unroll
        for (int j = 0; j < 6; ++j) { s += v[j]; s2 += v[j] * v[j]; }
#pragma unroll
        for (int m = 1; m < 64; m <<= 1) { s += __shfl_xor(s, m); s2 += __shfl_xor(s2, m); }
        float mu = s * (1.f / DIMD);
        float var = s2 * (1.f / DIMD) - mu * mu;
        float rs = rsqrtf(var + 1e-5f);
        bf16* orow = xn + (size_t)row * DIMD;
#pragma unroll
        for (int j = 0; j < 6; ++j) {
            int i = l + 64 * j;
            orow[i] = __float2bfloat16((v[j] - mu) * rs * g1[i] + b1[i]);
        }
    }
}

// ------------------------------------------- GEMM 128x128 (3-buffer pipeline)
template <int EPI, int NX, int KCN>
__global__ __launch_bounds__(256) void gemm128_k(const bf16* __restrict__ A,
                                                 const bf16* __restrict__ WT,
                                                 const float* __restrict__ bias,
                                                 bf16* __restrict__ ob0,
                                                 bf16* __restrict__ ob1,
                                                 bf16* __restrict__ ob2,
                                                 int K, int Nw) {
    __shared__ __align__(16) char Als[3][8192];
    __shared__ __align__(16) char Bls[3][8192];
    int tid = threadIdx.x;
    int w = tid >> 6, l = tid & 63;
    int c = l & 15, g = l >> 4;
    int wr = w >> 1, wc = w & 1;
    int swz = xcd_swz(blockIdx.x, gridDim.x);
    int m0 = (swz / NX) * 128, n0 = (swz % NX) * 128;
    const char* Ag = (const char*)A + (size_t)m0 * K * 2;
    const char* Bg = (const char*)WT + (size_t)n0 * K * 2;
    int K2 = K * 2;

    f32x4 acc[4][4];
#pragma unroll
    for (int mi = 0; mi < 4; ++mi)
#pragma unroll
        for (int ni = 0; ni < 4; ++ni) acc[mi][ni] = (f32x4){0.f, 0.f, 0.f, 0.f};

    auto stage = [&](int t, int bi) {
#pragma unroll
        for (int p = 0; p < 2; ++p) {
            int chunk = p * 256 + tid;
            int r = chunk >> 2;
            int cc = ((chunk & 3) ^ (r & 3)) << 4;
            gld16(Ag + (size_t)r * K2 + t * 64 + cc, &Als[bi][chunk * 16]);
            gld16(Bg + (size_t)r * K2 + t * 64 + cc, &Bls[bi][chunk * 16]);
        }
    };

    stage(0, 0);
    stage(1, 1);
#pragma unroll
    for (int t = 0; t < KCN; ++t) {
        asm volatile("s_waitcnt vmcnt(4)" ::: "memory");
        __builtin_amdgcn_sched_barrier(0);
        __builtin_amdgcn_s_barrier();
        __builtin_amdgcn_sched_barrier(0);

        int B0 = t % 3;
        bf16x8 af[4], bfr[4];
#pragma unroll
        for (int mi = 0; mi < 4; ++mi) {
            int row = wr * 64 + mi * 16 + c;
            __builtin_memcpy(&af[mi], &Als[B0][row * 64 + ((g ^ (row & 3)) << 4)], 16);
        }
#pragma unroll
        for (int ni = 0; ni < 4; ++ni) {
            int row = wc * 64 + ni * 16 + c;
            __builtin_memcpy(&bfr[ni], &Bls[B0][row * 64 + ((g ^ (row & 3)) << 4)], 16);
        }
        __builtin_amdgcn_s_setprio(1);
#pragma unroll
        for (int mi = 0; mi < 4; ++mi)
#pragma unroll
            for (int ni = 0; ni < 4; ++ni)
                acc[mi][ni] = mfma16(af[mi], bfr[ni], acc[mi][ni]);
        __builtin_amdgcn_s_setprio(0);

        __builtin_amdgcn_sched_barrier(0);
        int tn2 = t + 2 < KCN ? t + 2 : KCN - 1;
        stage(tn2, (t + 2) % 3);
        __builtin_amdgcn_sched_barrier(0);
    }

#pragma unroll
    for (int mi = 0; mi < 4; ++mi) {
#pragma unroll
        for (int ni = 0; ni < 4; ++ni) {
            int ntb = n0 + wc * 64 + ni * 16;
#pragma unroll
            for (int r = 0; r < 4; ++r) {
                int m = m0 + wr * 64 + mi * 16 + 4 * g + r;
                int n = ntb + c;
                float val = acc[mi][ni][r] + bias[n];
                if (EPI == 0) {
                    int which = ntb / DIMD;
                    int rem = ntb - which * DIMD;
                    int h = rem >> 6;
                    int d = (rem & 63) + c;
                    int b = m >> 11, s = m & (SEQ - 1);
                    if (which == 2) {
                        int slot = (s & ~31) + 8 * ((m & 15) >> 2) + 4 * ((m >> 4) & 1) + (m & 3);
                        ob2[(((size_t)b * NHEADS + h) * HD + d) * SEQ + slot] = __float2bfloat16(val);
                    } else {
                        if (which == 0) val *= SC2F;
                        bf16* dp = which == 0 ? ob0 : ob1;
                        dp[(((size_t)b * NHEADS + h) * SEQ + s) * HD + d] = __float2bfloat16(val);
                    }
                } else {
                    float ge = 0.5f * val * (1.0f + erff(val * 0.70710678118654752f));
                    ob0[(size_t)m * Nw + n] = __float2bfloat16(ge);
                }
            }
        }
    }
}

// ------------------------------- GEMM 64x64 (+resid, f32 out): proj / mlp2
template <int NX, int KCN>
__global__ __launch_bounds__(256) void gemm_k(const bf16* __restrict__ A,
                                              const bf16* __restrict__ WT,
                                              const float* __restrict__ bias,
                                              const float* __restrict__ resid,
                                              float* __restrict__ outf,
                                              int K, int Nw) {
    __shared__ __align__(16) char Als[3][8192];
    __shared__ __align__(16) char Bls[3][8192];
    int tid = threadIdx.x;
    int w = tid >> 6, l = tid & 63;
    int c = l & 15, g = l >> 4;
    int swz = xcd_swz(blockIdx.x, gridDim.x);
    int m0 = (swz / NX) * 64, n0 = (swz % NX) * 64;
    const char* Ag = (const char*)A + (size_t)m0 * K * 2;
    const char* Bg = (const char*)WT + (size_t)n0 * K * 2;
    int K2 = K * 2;

    f32x4 acc[4];
#pragma unroll
    for (int nt = 0; nt < 4; ++nt) acc[nt] = (f32x4){0.f, 0.f, 0.f, 0.f};

    auto stage = [&](int t, int bi) {
#pragma unroll
        for (int p = 0; p < 2; ++p) {
            int chunk = p * 256 + tid;
            int r = chunk >> 3;
            int cc = ((chunk & 7) ^ (r & 7)) << 4;
            gld16(Ag + (size_t)r * K2 + t * 128 + cc, &Als[bi][chunk * 16]);
            gld16(Bg + (size_t)r * K2 + t * 128 + cc, &Bls[bi][chunk * 16]);
        }
    };

    stage(0, 0);
    stage(1, 1);
    int arow = (16 * w + c) * 128;
    int sw = c & 7;
#pragma unroll
    for (int t = 0; t < KCN; ++t) {
        asm volatile("s_waitcnt vmcnt(4)" ::: "memory");
        __builtin_amdgcn_sched_barrier(0);
        __builtin_amdgcn_s_barrier();
        __builtin_amdgcn_sched_barrier(0);

        int B0 = t % 3;
#pragma unroll
        for (int kk = 0; kk < 2; ++kk) {
            int ch = ((kk * 4 + g) ^ sw) << 4;
            bf16x8 af;
            __builtin_memcpy(&af, &Als[B0][arow + ch], 16);
            bf16x8 bfr[4];
#pragma unroll
            for (int nt = 0; nt < 4; ++nt)
                __builtin_memcpy(&bfr[nt], &Bls[B0][(nt * 16 + c) * 128 + ch], 16);
            __builtin_amdgcn_s_setprio(1);
#pragma unroll
            for (int nt = 0; nt < 4; ++nt)
                acc[nt] = mfma16(af, bfr[nt], acc[nt]);
            __builtin_amdgcn_s_setprio(0);
        }

        __builtin_amdgcn_sched_barrier(0);
        int tn2 = t + 2 < KCN ? t + 2 : KCN - 1;
        stage(tn2, (t + 2) % 3);
        __builtin_amdgcn_sched_barrier(0);
    }

#pragma unroll
    for (int nt = 0; nt < 4; ++nt) {
        int ntb = n0 + nt * 16;
#pragma unroll
        for (int r = 0; r < 4; ++r) {
            int m = m0 + 16 * w + 4 * g + r;
            int n = ntb + c;
            float val = acc[nt][r] + bias[n];
            val += resid[(size_t)m * Nw + n];
            outf[(size_t)m * Nw + n] = val;
        }
    }
}

// ---------------------------------------------------------------- Attention
// KV-split: each block handles 1024 keys (32 tiles of 32) for its (bh,qt).
// Grid 1536 -> 6 blocks/CU with 24KB LDS. Writes UNNORMALIZED partial O (bf16)
// + partial row-sum; reduce_k combines: O = (O0+O1)/(l0+l1).
__global__ __launch_bounds__(256) void attn_k(const bf16* __restrict__ q,
                                              const bf16* __restrict__ k,
                                              const bf16* __restrict__ vT,
                                              const bf16* __restrict__ DP,
                                              bf16* __restrict__ opart,
                                              float* __restrict__ lsum) {
    __shared__ __align__(16) char Kls[3][4096];   // K  [32 k-rows][64 d]
    __shared__ __align__(16) char Vls[3][4096];   // V^T[64 d-rows][32 k] (permuted)

    int tid = threadIdx.x;
    int w = tid >> 6, l = tid & 63;
    int lq = l & 15, g = l >> 4;
    int swzb = xcd_swz(blockIdx.x, gridDim.x);
    int qt = swzb & 31;
    int bhh = swzb >> 5;           // bh*2 + half
    int half = bhh & 1;
    int bh = bhh >> 1;
    int b = bh / NHEADS, h = bh % NHEADS;
    int qrow = qt * 64 + w * 16 + lq;

    const bf16* qp = q + ((size_t)bh * SEQ + qrow) * HD + 8 * g;
    bf16x8 qf0 = *(const bf16x8*)qp;
    bf16x8 qf1 = *(const bf16x8*)(qp + 32);

    const char* kgb = (const char*)(k + (size_t)bh * SEQ * HD) + (size_t)half * 131072;
    const char* vgb = (const char*)(vT + (size_t)bh * HD * SEQ) + (size_t)half * 2048;
    const char* dpb = (const char*)DP + ((size_t)((b * 32 + qt) * 4 + w)) * 65536
                      + (size_t)half * 32768 + l * 16;

    f32x4 oacc[4];
#pragma unroll
    for (int dt = 0; dt < 4; ++dt) oacc[dt] = (f32x4){0.f, 0.f, 0.f, 0.f};
    f32x4 osum = (f32x4){0.f, 0.f, 0.f, 0.f};
    bf16x8 ones = {(short)0x3F80, (short)0x3F80, (short)0x3F80, (short)0x3F80,
                   (short)0x3F80, (short)0x3F80, (short)0x3F80, (short)0x3F80};

    int swq = lq & 7;
    int offA = lq * 128 + ((g ^ swq) << 4);                       // K lo
    int offB = lq * 128 + (((4 + g) ^ swq) << 4);                 // K hi
    int offV = lq * 64 + (((g ^ (lq & 3) ^ ((lq >> 2) & 3)) & 3) << 4);  // V

    auto stage = [&](int t, int B2) {
        {   // K tile: 32 rows x 128B
            int r = tid >> 3, c = tid & 7;
            int cc = (c ^ (r & 7)) << 4;
            gld16(kgb + (size_t)t * 4096 + r * 128 + cc, &Kls[B2][tid * 16]);
        }
        {   // V tile: 64 d-rows x 64B, chunk swizzle (c ^ r&3 ^ (r>>2)&3)
            int r = tid >> 2, c = tid & 3;
            int cc = ((c ^ (r & 3) ^ ((r >> 2) & 3)) & 3) << 4;
            gld16(vgb + (size_t)r * 4096 + t * 64 + cc, &Vls[B2][tid * 16]);
        }
    };

    stage(0, 0);
    uint4 cdp = *(const uint4*)(dpb);
    stage(1, 1);

    auto body = [&](int t, int B0, int B2) {
        // drain stage(t)+dp(t); leave stage(t+1)'s 2 loads in flight
        asm volatile("s_waitcnt vmcnt(2)" ::: "memory");
        __builtin_amdgcn_sched_barrier(0);
        __builtin_amdgcn_s_barrier();
        __builtin_amdgcn_sched_barrier(0);

        const char* Kb = &Kls[B0][0];
        const char* Vb = &Vls[B0][0];
        f32x4 bc[2];
        bc[0] = (f32x4){bflo(cdp.x), bfhi(cdp.x), bflo(cdp.y), bfhi(cdp.y)};
        bc[1] = (f32x4){bflo(cdp.z), bfhi(cdp.z), bflo(cdp.w), bfhi(cdp.w)};
        f32x4 st[2];
        __builtin_amdgcn_s_setprio(1);
#pragma unroll
        for (int s = 0; s < 2; ++s) {
            bf16x8 klo, khi;
            __builtin_memcpy(&klo, Kb + s * 2048 + offA, 16);
            __builtin_memcpy(&khi, Kb + s * 2048 + offB, 16);
            st[s] = mfma16(klo, qf0, bc[s]);
            st[s] = mfma16(khi, qf1, st[s]);
        }
        __builtin_amdgcn_s_setprio(0);

        float p[8];
        p[0] = fexp2(st[0][0]);
        p[1] = fexp2(st[0][1]);
        p[2] = fexp2(st[0][2]);
        p[3] = fexp2(st[0][3]);
        p[4] = fexp2(st[1][0]);
        p[5] = fexp2(st[1][1]);
        p[6] = fexp2(st[1][2]);
        p[7] = fexp2(st[1][3]);

        unsigned int pw[4];
        pw[0] = cvtpk(p[0], p[1]);
        pw[1] = cvtpk(p[2], p[3]);
        pw[2] = cvtpk(p[4], p[5]);
        pw[3] = cvtpk(p[6], p[7]);
        bf16x8 pf;
        __builtin_memcpy(&pf, pw, 16);

        __builtin_amdgcn_s_setprio(1);
        osum = mfma16(ones, pf, osum);
#pragma unroll
        for (int dt = 0; dt < 4; ++dt) {
            bf16x8 vf;
            __builtin_memcpy(&vf, Vb + dt * 1024 + offV, 16);
            oacc[dt] = mfma16(vf, pf, oacc[dt]);
        }
        __builtin_amdgcn_s_setprio(0);

        __builtin_amdgcn_sched_barrier(0);
        int tn1 = t + 1 < 32 ? t + 1 : 31;
        uint4 nd = *(const uint4*)(dpb + (size_t)tn1 * 1024);
        __builtin_amdgcn_sched_barrier(0);
        int tn2 = t + 2 < 32 ? t + 2 : 31;
        stage(tn2, B2);
        __builtin_amdgcn_sched_barrier(0);
        cdp = nd;
    };

    for (int t = 0; t < 30; t += 3) {
        body(t + 0, 0, 2);
        body(t + 1, 1, 0);
        body(t + 2, 2, 1);
    }
    body(30, 0, 2);
    body(31, 1, 0);

    // write unnormalized partial O + row-sum
    bf16* op = opart + (size_t)half * NTOK * DIMD
               + ((size_t)b * SEQ + qrow) * DIMD + h * HD + 4 * g;
#pragma unroll
    for (int dt = 0; dt < 4; ++dt) {
        unsigned int t2[2];
        t2[0] = cvtpk(oacc[dt][0], oacc[dt][1]);
        t2[1] = cvtpk(oacc[dt][2], oacc[dt][3]);
        __builtin_memcpy(op + dt * 16, t2, 8);
    }
    if (g == 0) lsum[(size_t)bhh * SEQ + qrow] = osum[0];
}

// -------------------------------------- combine the two attention halves
__global__ __launch_bounds__(256) void reduce_k(const bf16* __restrict__ opart,
                                                const float* __restrict__ lsum,
                                                bf16* __restrict__ ao) {
    size_t f = ((size_t)blockIdx.x * 256 + threadIdx.x) * 8;
    int sg = (int)(f / DIMD);                 // b*SEQ + s
    int rem = (int)(f - (size_t)sg * DIMD);
    int h = rem >> 6;
    int b = sg >> 11;
    int s = sg & (SEQ - 1);
    int bh2 = (b * NHEADS + h) * 2;
    float l0 = lsum[(size_t)bh2 * SEQ + s];
    float l1 = lsum[(size_t)(bh2 + 1) * SEQ + s];
    float inv = 1.f / (l0 + l1);
    const unsigned int* p0 = (const unsigned int*)(opart + f);
    const unsigned int* p1 = (const unsigned int*)(opart + (size_t)NTOK * DIMD + f);
    uint4 u0 = *(const uint4*)p0;
    uint4 u1 = *(const uint4*)p1;
    unsigned int o[4];
    o[0] = cvtpk((bflo(u0.x) + bflo(u1.x)) * inv, (bfhi(u0.x) + bfhi(u1.x)) * inv);
    o[1] = cvtpk((bflo(u0.y) + bflo(u1.y)) * inv, (bfhi(u0.y) + bfhi(u1.y)) * inv);
    o[2] = cvtpk((bflo(u0.z) + bflo(u1.z)) * inv, (bfhi(u0.z) + bfhi(u1.z)) * inv);
    o[3] = cvtpk((bflo(u0.w) + bflo(u1.w)) * inv, (bfhi(u0.w) + bfhi(u1.w)) * inv);
    *(uint4*)(ao + f) = *(uint4*)o;
}

// ---------------------------------------------------------------- launch
extern "C" void kernel_launch(void* const* d_in, const int* in_sizes, int n_in,
                              void* d_out, int out_size, void* d_ws, size_t ws_size,
                              hipStream_t stream) {
    const float* x      = (const float*)d_in[0];
    const float* pos    = (const float*)d_in[1];
    const float* qkv_w  = (const float*)d_in[2];
    const float* qkv_b  = (const float*)d_in[3];
    const float* proj_w = (const float*)d_in[4];
    const float* proj_b = (const float*)d_in[5];
    const float* mlp_w1 = (const float*)d_in[6];
    const float* mlp_b1 = (const float*)d_in[7];
    const float* mlp_w2 = (const float*)d_in[8];
    const float* mlp_b2 = (const float*)d_in[9];
    const float* ln1_g  = (const float*)d_in[10];
    const float* ln1_b  = (const float*)d_in[11];
    const float* ln2_g  = (const float*)d_in[12];
    const float* ln2_b  = (const float*)d_in[13];

    char* p = (char*)d_ws;
    size_t off = 0;
    auto alloc = [&](size_t bytes) {
        char* r = p + off;
        off = (off + bytes + 255) & ~(size_t)255;
        return r;
    };
    bf16* WT1 = (bf16*)alloc((size_t)1152 * 384 * 2);
    bf16* WT2 = (bf16*)alloc((size_t)384 * 384 * 2);
    bf16* WT3 = (bf16*)alloc((size_t)384 * 768 * 2);
    bf16* WT4 = (bf16*)alloc((size_t)768 * 384 * 2);
    bf16* xn  = (bf16*)alloc((size_t)NTOK * DIMD * 2);
    bf16* xn2 = (bf16*)alloc((size_t)NTOK * DIMD * 2);
    bf16* qb  = (bf16*)alloc((size_t)NTOK * DIMD * 2);
    bf16* kb  = (bf16*)alloc((size_t)NTOK * DIMD * 2);
    bf16* vTb = (bf16*)alloc((size_t)NTOK * DIMD * 2);
    bf16* ao  = (bf16*)alloc((size_t)NTOK * DIMD * 2);
    float* x1 = (float*)alloc((size_t)NTOK * DIMD * 4);
    bf16* hh  = (bf16*)alloc((size_t)NTOK * MLPH * 2);   // also attn partial-O
    bf16* dtab = (bf16*)alloc((size_t)NBATCH * SEQ * SEQ * 2);  // 32 MiB (DP)
    float* lsum = (float*)alloc((size_t)2 * NBATCH * NHEADS * SEQ * 4);
    if (off > ws_size) return;  // workspace too small; cannot run

    prep_k<<<1152 + 512 + 2048, 256, 0, stream>>>(
        qkv_w, proj_w, mlp_w1, mlp_w2, WT1, WT2, WT3, WT4,
        pos, dtab, x, ln1_g, ln1_b, xn);

    // qkv GEMM -> q(pre-scaled), k, vT(transposed+permuted); grid 9x64 -> 576
    gemm128_k<0, 9, 12><<<576, 256, 0, stream>>>(
        xn, WT1, qkv_b, qb, kb, vTb, 384, 1152);
    // attention, KV-split x2 -> partials in hh + lsum
    attn_k<<<NBATCH * NHEADS * 2 * 32, 256, 0, stream>>>(qb, kb, vTb, dtab, hh, lsum);
    reduce_k<<<NTOK * DIMD / 2048, 256, 0, stream>>>(hh, lsum, ao);
    // proj + residual -> x1 (f32); grid 6x128 -> 768; KCN = 6
    gemm_k<6, 6><<<768, 256, 0, stream>>>(
        ao, WT2, proj_b, x, x1, 384, 384);
    ln_k<<<NTOK / 4, 256, 0, stream>>>(x1, ln2_g, ln2_b, xn2);
    // mlp1 + gelu -> hh; grid 6x64 -> 384; KCN = 12
    gemm128_k<2, 6, 12><<<384, 256, 0, stream>>>(
        xn2, WT3, mlp_b1, hh, nullptr, nullptr, 384, 768);
    // mlp2 + residual -> out (f32); grid 6x128 -> 768; KCN = 12
    gemm_k<6, 12><<<768, 256, 0, stream>>>(
        hh, WT4, mlp_b2, x1, (float*)d_out, 768, 384);
}

// Round 18
// 125.978 us; speedup vs baseline: 1.1226x; 1.1226x over previous
//
#include <hip/hip_runtime.h>
#include <hip/hip_bf16.h>
#include <math.h>

#define DIMD 384
#define NHEADS 6
#define HD 64
#define MLPH 768
#define SEQ 2048
#define NBATCH 4
#define NTOK (NBATCH*SEQ)   // 8192

typedef __hip_bfloat16 bf16;

typedef __attribute__((ext_vector_type(8))) short bf16x8;
typedef __attribute__((ext_vector_type(4))) float f32x4;

#define LOG2E 1.44269504088896340736f
#define SC2F 0.18033688011112042f   // 0.125 * log2(e), folded into Q

static __device__ inline float fexp2(float x) { return __builtin_amdgcn_exp2f(x); }

static __device__ inline f32x4 mfma16(bf16x8 a, bf16x8 b, f32x4 c) {
    return __builtin_amdgcn_mfma_f32_16x16x32_bf16(a, b, c, 0, 0, 0);
}

// packed f32x2 -> bf16x2 (RNE), single instruction
static __device__ inline unsigned int cvtpk(float lo, float hi) {
    unsigned int r;
    asm("v_cvt_pk_bf16_f32 %0, %1, %2" : "=v"(r) : "v"(lo), "v"(hi));
    return r;
}
static __device__ inline float bflo(unsigned int u) { return __builtin_bit_cast(float, u << 16); }
static __device__ inline float bfhi(unsigned int u) { return __builtin_bit_cast(float, u & 0xffff0000u); }

// async global->LDS, 16B per lane. LDS dest must be wave-linear (base + lane*16).
static __device__ inline void gld16(const void* g, void* l) {
    __builtin_amdgcn_global_load_lds(
        (const __attribute__((address_space(1))) unsigned int*)g,
        (__attribute__((address_space(3))) unsigned int*)l, 16, 0, 0);
}

// XCD-aware swizzle: hw workgroup i lands on XCD i%8; remap so each XCD gets
// a CONTIGUOUS semantic range. Requires gridDim.x % 8 == 0.
static __device__ inline int xcd_swz(int wg, int nwg) {
    return (wg & 7) * (nwg >> 3) + (wg >> 3);
}

// ---------------------------------------------------------------- LayerNorm
__global__ __launch_bounds__(256) void ln_k(const float* __restrict__ x,
                                            const float* __restrict__ gm,
                                            const float* __restrict__ bt,
                                            bf16* __restrict__ out) {
    int row = blockIdx.x * 4 + (threadIdx.x >> 6);
    int l = threadIdx.x & 63;
    const float* xr = x + (size_t)row * DIMD;
    float v[6];
#pragma unroll
    for (int j = 0; j < 6; ++j) v[j] = xr[l + 64 * j];
    float s = 0.f, s2 = 0.f;
#pragma unroll
    for (int j = 0; j < 6; ++j) { s += v[j]; s2 += v[j] * v[j]; }
#pragma unroll
    for (int m = 1; m < 64; m <<= 1) { s += __shfl_xor(s, m); s2 += __shfl_xor(s2, m); }
    float mu = s * (1.f / DIMD);
    float var = s2 * (1.f / DIMD) - mu * mu;
    float rs = rsqrtf(var + 1e-5f);
    bf16* orow = out + (size_t)row * DIMD;
#pragma unroll
    for (int j = 0; j < 6; ++j) {
        int i = l + 64 * j;
        orow[i] = __float2bfloat16((v[j] - mu) * rs * gm[i] + bt[i]);
    }
}

// --------------------------------- prep: wtrans x4 + dist table + ln1, fused
__global__ __launch_bounds__(256) void prep_k(const float* __restrict__ w1,
                                              const float* __restrict__ w2,
                                              const float* __restrict__ w3,
                                              const float* __restrict__ w4,
                                              bf16* __restrict__ o1,
                                              bf16* __restrict__ o2,
                                              bf16* __restrict__ o3,
                                              bf16* __restrict__ o4,
                                              const float* __restrict__ pos,
                                              bf16* __restrict__ DP,
                                              const float* __restrict__ x,
                                              const float* __restrict__ g1,
                                              const float* __restrict__ b1,
                                              bf16* __restrict__ xn) {
    __shared__ float shbuf[6144];     // union: wtrans t[32][33] | dist pos cache
    int id = blockIdx.x;
    if (id < 1152) {
        float (*t)[33] = (float(*)[33])shbuf;
        const float* W; bf16* O; int K, N;
        if (id < 432)      { W = w1; O = o1; K = 384; N = 1152; }
        else if (id < 576) { W = w2; O = o2; K = 384; N = 384;  id -= 432; }
        else if (id < 864) { W = w3; O = o3; K = 384; N = 768;  id -= 576; }
        else               { W = w4; O = o4; K = 768; N = 384;  id -= 864; }
        int nbx = N >> 5;
        int nb = (id % nbx) * 32, kb = (id / nbx) * 32;
        int tx = threadIdx.x & 31, ty = threadIdx.x >> 5;
#pragma unroll
        for (int i = 0; i < 4; ++i)
            t[ty + 8 * i][tx] = W[(size_t)(kb + ty + 8 * i) * N + nb + tx];
        __syncthreads();
#pragma unroll
        for (int i = 0; i < 4; ++i)
            O[(size_t)(nb + ty + 8 * i) * K + kb + tx] = __float2bfloat16(t[tx][ty + 8 * i]);
    } else if (id < 1664) {
        int blk = id - 1152;              // (b*32+qt)*4 + w
        int w = blk & 3, qt = (blk >> 2) & 31, b = blk >> 7;
        int l = threadIdx.x & 63, tt = threadIdx.x >> 6;
        int lq = l & 15, g = l >> 4;
        const float* posb = pos + (size_t)b * SEQ * 3;
        for (int i = threadIdx.x; i < 1536; i += 256)
            ((f32x4*)shbuf)[i] = ((const f32x4*)posb)[i];
        __syncthreads();
        int q = qt * 64 + w * 16 + lq;
        float px = shbuf[3 * q], py = shbuf[3 * q + 1], pz = shbuf[3 * q + 2];
        char* base = (char*)DP + (size_t)blk * 65536;
        for (int j = 0; j < 8; ++j) {
            int tt8 = tt * 8 + j;
#pragma unroll
            for (int m = 0; m < 2; ++m) {
                int k0 = tt8 * 64 + 32 * m + 4 * g;
                float a[24];
                *(f32x4*)&a[0]  = *(const f32x4*)&shbuf[3 * k0];
                *(f32x4*)&a[4]  = *(const f32x4*)&shbuf[3 * k0 + 4];
                *(f32x4*)&a[8]  = *(const f32x4*)&shbuf[3 * k0 + 8];
                *(f32x4*)&a[12] = *(const f32x4*)&shbuf[3 * (k0 + 16)];
                *(f32x4*)&a[16] = *(const f32x4*)&shbuf[3 * (k0 + 16) + 4];
                *(f32x4*)&a[20] = *(const f32x4*)&shbuf[3 * (k0 + 16) + 8];
                float o8[8];
#pragma unroll
                for (int r = 0; r < 8; ++r) {
                    float dx = px - a[3 * r], dy = py - a[3 * r + 1], dz = pz - a[3 * r + 2];
                    o8[r] = fexp2(-LOG2E * (dx * dx + dy * dy + dz * dz)) * LOG2E;
                }
                uint4 o;
                o.x = cvtpk(o8[0], o8[1]); o.y = cvtpk(o8[2], o8[3]);
                o.z = cvtpk(o8[4], o8[5]); o.w = cvtpk(o8[6], o8[7]);
                *(uint4*)(base + ((size_t)tt8 * 2 + m) * 1024 + l * 16) = o;
            }
        }
    } else {
        int row = (id - 1664) * 4 + (threadIdx.x >> 6);
        int l = threadIdx.x & 63;
        const float* xr = x + (size_t)row * DIMD;
        float v[6];
#pragma unroll
        for (int j = 0; j < 6; ++j) v[j] = xr[l + 64 * j];
        float s = 0.f, s2 = 0.f;
#pragma unroll
        for (int j = 0; j < 6; ++j) { s += v[j]; s2 += v[j] * v[j]; }
#pragma unroll
        for (int m = 1; m < 64; m <<= 1) { s += __shfl_xor(s, m); s2 += __shfl_xor(s2, m); }
        float mu = s * (1.f / DIMD);
        float var = s2 * (1.f / DIMD) - mu * mu;
        float rs = rsqrtf(var + 1e-5f);
        bf16* orow = xn + (size_t)row * DIMD;
#pragma unroll
        for (int j = 0; j < 6; ++j) {
            int i = l + 64 * j;
            orow[i] = __float2bfloat16((v[j] - mu) * rs * g1[i] + b1[i]);
        }
    }
}

// ------------------------------------------- GEMM 128x128 (m97 structure)
// 3-buffer counted-vmcnt pipeline. KCN = K/32 compile-time.
// EPI 0: qkv scatter (Q pre-scaled; V transposed+PV-permuted); 2: gelu.
template <int EPI, int NX, int KCN>
__global__ __launch_bounds__(256) void gemm128_k(const bf16* __restrict__ A,
                                                 const bf16* __restrict__ WT,
                                                 const float* __restrict__ bias,
                                                 bf16* __restrict__ ob0,
                                                 bf16* __restrict__ ob1,
                                                 bf16* __restrict__ ob2,
                                                 int K, int Nw) {
    __shared__ __align__(16) char Als[3][8192];   // [128 m][32 k] bf16
    __shared__ __align__(16) char Bls[3][8192];   // [128 n][32 k] bf16
    int tid = threadIdx.x;
    int w = tid >> 6, l = tid & 63;
    int c = l & 15, g = l >> 4;
    int wr = w >> 1, wc = w & 1;
    int swz = xcd_swz(blockIdx.x, gridDim.x);
    int m0 = (swz / NX) * 128, n0 = (swz % NX) * 128;
    const char* Ag = (const char*)A + (size_t)m0 * K * 2;
    const char* Bg = (const char*)WT + (size_t)n0 * K * 2;
    int K2 = K * 2;

    f32x4 acc[4][4];
#pragma unroll
    for (int mi = 0; mi < 4; ++mi)
#pragma unroll
        for (int ni = 0; ni < 4; ++ni) acc[mi][ni] = (f32x4){0.f, 0.f, 0.f, 0.f};

    auto stage = [&](int t, int bi) {
#pragma unroll
        for (int p = 0; p < 2; ++p) {
            int chunk = p * 256 + tid;            // 512 x 16B per 8KB tile
            int r = chunk >> 2;                   // row 0..127 (64B rows)
            int cc = ((chunk & 3) ^ (r & 3)) << 4;
            gld16(Ag + (size_t)r * K2 + t * 64 + cc, &Als[bi][chunk * 16]);
            gld16(Bg + (size_t)r * K2 + t * 64 + cc, &Bls[bi][chunk * 16]);
        }
    };

    stage(0, 0);
    stage(1, 1);
#pragma unroll
    for (int t = 0; t < KCN; ++t) {
        asm volatile("s_waitcnt vmcnt(4)" ::: "memory");
        __builtin_amdgcn_sched_barrier(0);
        __builtin_amdgcn_s_barrier();
        __builtin_amdgcn_sched_barrier(0);

        int B0 = t % 3;
        bf16x8 af[4], bfr[4];
#pragma unroll
        for (int mi = 0; mi < 4; ++mi) {
            int row = wr * 64 + mi * 16 + c;
            __builtin_memcpy(&af[mi], &Als[B0][row * 64 + ((g ^ (row & 3)) << 4)], 16);
        }
#pragma unroll
        for (int ni = 0; ni < 4; ++ni) {
            int row = wc * 64 + ni * 16 + c;
            __builtin_memcpy(&bfr[ni], &Bls[B0][row * 64 + ((g ^ (row & 3)) << 4)], 16);
        }
        __builtin_amdgcn_s_setprio(1);
#pragma unroll
        for (int mi = 0; mi < 4; ++mi)
#pragma unroll
            for (int ni = 0; ni < 4; ++ni)
                acc[mi][ni] = mfma16(af[mi], bfr[ni], acc[mi][ni]);
        __builtin_amdgcn_s_setprio(0);

        __builtin_amdgcn_sched_barrier(0);
        int tn2 = t + 2 < KCN ? t + 2 : KCN - 1;
        stage(tn2, (t + 2) % 3);
        __builtin_amdgcn_sched_barrier(0);
    }

#pragma unroll
    for (int mi = 0; mi < 4; ++mi) {
#pragma unroll
        for (int ni = 0; ni < 4; ++ni) {
            int ntb = n0 + wc * 64 + ni * 16;
#pragma unroll
            for (int r = 0; r < 4; ++r) {
                int m = m0 + wr * 64 + mi * 16 + 4 * g + r;
                int n = ntb + c;
                float val = acc[mi][ni][r] + bias[n];
                if (EPI == 0) {
                    int which = ntb / DIMD;
                    int rem = ntb - which * DIMD;
                    int h = rem >> 6;
                    int d = (rem & 63) + c;
                    int b = m >> 11, s = m & (SEQ - 1);
                    if (which == 2) {
                        int slot = (s & ~31) + 8 * ((m & 15) >> 2) + 4 * ((m >> 4) & 1) + (m & 3);
                        ob2[(((size_t)b * NHEADS + h) * HD + d) * SEQ + slot] = __float2bfloat16(val);
                    } else {
                        if (which == 0) val *= SC2F;
                        bf16* dp = which == 0 ? ob0 : ob1;
                        dp[(((size_t)b * NHEADS + h) * SEQ + s) * HD + d] = __float2bfloat16(val);
                    }
                } else {
                    float ge = 0.5f * val * (1.0f + erff(val * 0.70710678118654752f));
                    ob0[(size_t)m * Nw + n] = __float2bfloat16(ge);
                }
            }
        }
    }
}

// ------------------------------- GEMM 64x64 (+resid, f32 out): proj / mlp2
template <int NX, int KCN>
__global__ __launch_bounds__(256) void gemm_k(const bf16* __restrict__ A,
                                              const bf16* __restrict__ WT,
                                              const float* __restrict__ bias,
                                              const float* __restrict__ resid,
                                              float* __restrict__ outf,
                                              int K, int Nw) {
    __shared__ __align__(16) char Als[3][8192];
    __shared__ __align__(16) char Bls[3][8192];
    int tid = threadIdx.x;
    int w = tid >> 6, l = tid & 63;
    int c = l & 15, g = l >> 4;
    int swz = xcd_swz(blockIdx.x, gridDim.x);
    int m0 = (swz / NX) * 64, n0 = (swz % NX) * 64;
    const char* Ag = (const char*)A + (size_t)m0 * K * 2;
    const char* Bg = (const char*)WT + (size_t)n0 * K * 2;
    int K2 = K * 2;

    f32x4 acc[4];
#pragma unroll
    for (int nt = 0; nt < 4; ++nt) acc[nt] = (f32x4){0.f, 0.f, 0.f, 0.f};

    auto stage = [&](int t, int bi) {
#pragma unroll
        for (int p = 0; p < 2; ++p) {
            int chunk = p * 256 + tid;
            int r = chunk >> 3;
            int cc = ((chunk & 7) ^ (r & 7)) << 4;
            gld16(Ag + (size_t)r * K2 + t * 128 + cc, &Als[bi][chunk * 16]);
            gld16(Bg + (size_t)r * K2 + t * 128 + cc, &Bls[bi][chunk * 16]);
        }
    };

    stage(0, 0);
    stage(1, 1);
    int arow = (16 * w + c) * 128;
    int sw = c & 7;
#pragma unroll
    for (int t = 0; t < KCN; ++t) {
        asm volatile("s_waitcnt vmcnt(4)" ::: "memory");
        __builtin_amdgcn_sched_barrier(0);
        __builtin_amdgcn_s_barrier();
        __builtin_amdgcn_sched_barrier(0);

        int B0 = t % 3;
#pragma unroll
        for (int kk = 0; kk < 2; ++kk) {
            int ch = ((kk * 4 + g) ^ sw) << 4;
            bf16x8 af;
            __builtin_memcpy(&af, &Als[B0][arow + ch], 16);
            bf16x8 bfr[4];
#pragma unroll
            for (int nt = 0; nt < 4; ++nt)
                __builtin_memcpy(&bfr[nt], &Bls[B0][(nt * 16 + c) * 128 + ch], 16);
            __builtin_amdgcn_s_setprio(1);
#pragma unroll
            for (int nt = 0; nt < 4; ++nt)
                acc[nt] = mfma16(af, bfr[nt], acc[nt]);
            __builtin_amdgcn_s_setprio(0);
        }

        __builtin_amdgcn_sched_barrier(0);
        int tn2 = t + 2 < KCN ? t + 2 : KCN - 1;
        stage(tn2, (t + 2) % 3);
        __builtin_amdgcn_sched_barrier(0);
    }

#pragma unroll
    for (int nt = 0; nt < 4; ++nt) {
        int ntb = n0 + nt * 16;
#pragma unroll
        for (int r = 0; r < 4; ++r) {
            int m = m0 + 16 * w + 4 * g + r;
            int n = ntb + c;
            float val = acc[nt][r] + bias[n];
            val += resid[(size_t)m * Nw + n];
            outf[(size_t)m * Nw + n] = val;
        }
    }
}

// ---------------------------------------------------------------- Attention
// Best config (round 15): 4 waves x 16 q-rows, KBLK=64, 3-buffer counted-vmcnt
// pipeline unrolled x3, dist bias as MFMA C-input (Q carries softmax scale),
// ones-MFMA row sum, PV-permuted V columns, XCD swizzle.
__global__ __launch_bounds__(256) void attn_k(const bf16* __restrict__ q,
                                              const bf16* __restrict__ k,
                                              const bf16* __restrict__ vT,
                                              const bf16* __restrict__ DP,
                                              bf16* __restrict__ out) {
    __shared__ __align__(16) char Kls[3][8192];   // K  [64 k-rows][64 d]
    __shared__ __align__(16) char Vls[3][8192];   // V^T[64 d-rows][64 k] (permuted cols)

    int tid = threadIdx.x;
    int w = tid >> 6, l = tid & 63;
    int lq = l & 15, g = l >> 4;
    int swzb = xcd_swz(blockIdx.x, gridDim.x);
    int qt = swzb & 31;
    int bh = swzb >> 5;
    int b = bh / NHEADS, h = bh % NHEADS;
    int qrow = qt * 64 + w * 16 + lq;

    const bf16* qp = q + ((size_t)bh * SEQ + qrow) * HD + 8 * g;
    bf16x8 qf0 = *(const bf16x8*)qp;
    bf16x8 qf1 = *(const bf16x8*)(qp + 32);

    const char* kgb = (const char*)(k + (size_t)bh * SEQ * HD);
    const char* vgb = (const char*)(vT + (size_t)bh * HD * SEQ);
    const char* dpb = (const char*)DP + ((size_t)((b * 32 + qt) * 4 + w)) * 65536 + l * 16;

    f32x4 oacc[4];
#pragma unroll
    for (int dt = 0; dt < 4; ++dt) oacc[dt] = (f32x4){0.f, 0.f, 0.f, 0.f};
    f32x4 osum = (f32x4){0.f, 0.f, 0.f, 0.f};
    bf16x8 ones = {(short)0x3F80, (short)0x3F80, (short)0x3F80, (short)0x3F80,
                   (short)0x3F80, (short)0x3F80, (short)0x3F80, (short)0x3F80};

    int swq = lq & 7;
    int offA = lq * 128 + ((g ^ swq) << 4);
    int offB = lq * 128 + (((4 + g) ^ swq) << 4);

    auto stage = [&](int t, int B2) {
#pragma unroll
        for (int p = 0; p < 2; ++p) {
            int chunk = p * 256 + tid;
            int r = chunk >> 3, c = chunk & 7;
            int cc = (c ^ (r & 7)) << 4;
            gld16(kgb + (size_t)t * 8192 + r * 128 + cc, &Kls[B2][chunk * 16]);
            gld16(vgb + (size_t)r * 4096 + t * 128 + cc, &Vls[B2][chunk * 16]);
        }
    };

    stage(0, 0);
    uint4 cdp0 = *(const uint4*)(dpb);
    uint4 cdp1 = *(const uint4*)(dpb + 1024);
    stage(1, 1);

    auto body = [&](int t, int B0, int B2) {
        asm volatile("s_waitcnt vmcnt(4)" ::: "memory");
        __builtin_amdgcn_sched_barrier(0);
        __builtin_amdgcn_s_barrier();
        __builtin_amdgcn_sched_barrier(0);

        const char* Kb = &Kls[B0][0];
        const char* Vb = &Vls[B0][0];
        f32x4 bc[4];
        bc[0] = (f32x4){bflo(cdp0.x), bfhi(cdp0.x), bflo(cdp0.y), bfhi(cdp0.y)};
        bc[1] = (f32x4){bflo(cdp0.z), bfhi(cdp0.z), bflo(cdp0.w), bfhi(cdp0.w)};
        bc[2] = (f32x4){bflo(cdp1.x), bfhi(cdp1.x), bflo(cdp1.y), bfhi(cdp1.y)};
        bc[3] = (f32x4){bflo(cdp1.z), bfhi(cdp1.z), bflo(cdp1.w), bfhi(cdp1.w)};
        f32x4 st[4];
        __builtin_amdgcn_s_setprio(1);
#pragma unroll
        for (int s = 0; s < 4; ++s) {
            bf16x8 klo, khi;
            __builtin_memcpy(&klo, Kb + s * 2048 + offA, 16);
            __builtin_memcpy(&khi, Kb + s * 2048 + offB, 16);
            st[s] = mfma16(klo, qf0, bc[s]);
            st[s] = mfma16(khi, qf1, st[s]);
        }
        __builtin_amdgcn_s_setprio(0);

#pragma unroll
        for (int m = 0; m < 2; ++m) {
            int offV = m == 0 ? offA : offB;
            f32x4 s0v = st[2 * m], s1v = st[2 * m + 1];
            float p[8];
            p[0] = fexp2(s0v[0]);
            p[1] = fexp2(s0v[1]);
            p[2] = fexp2(s0v[2]);
            p[3] = fexp2(s0v[3]);
            p[4] = fexp2(s1v[0]);
            p[5] = fexp2(s1v[1]);
            p[6] = fexp2(s1v[2]);
            p[7] = fexp2(s1v[3]);

            unsigned int pw[4];
            pw[0] = cvtpk(p[0], p[1]);
            pw[1] = cvtpk(p[2], p[3]);
            pw[2] = cvtpk(p[4], p[5]);
            pw[3] = cvtpk(p[6], p[7]);
            bf16x8 pf;
            __builtin_memcpy(&pf, pw, 16);

            __builtin_amdgcn_s_setprio(1);
            osum = mfma16(ones, pf, osum);
#pragma unroll
            for (int dt = 0; dt < 4; ++dt) {
                bf16x8 vf;
                __builtin_memcpy(&vf, Vb + dt * 2048 + offV, 16);
                oacc[dt] = mfma16(vf, pf, oacc[dt]);
            }
            __builtin_amdgcn_s_setprio(0);
        }

        __builtin_amdgcn_sched_barrier(0);
        int tn1 = t + 1 < 32 ? t + 1 : 31;
        const char* dpn = dpb + (size_t)tn1 * 2048;
        uint4 n0 = *(const uint4*)(dpn);
        uint4 n1 = *(const uint4*)(dpn + 1024);
        __builtin_amdgcn_sched_barrier(0);
        int tn2 = t + 2 < 32 ? t + 2 : 31;
        stage(tn2, B2);
        __builtin_amdgcn_sched_barrier(0);
        cdp0 = n0; cdp1 = n1;
    };

    for (int t = 0; t < 30; t += 3) {
        body(t + 0, 0, 2);
        body(t + 1, 1, 0);
        body(t + 2, 2, 1);
    }
    body(30, 0, 2);
    body(31, 1, 0);

    float inv = 1.f / osum[0];      // every lane holds the full row denominator
    bf16* op = out + ((size_t)b * SEQ + qrow) * DIMD + h * HD + 4 * g;
#pragma unroll
    for (int dt = 0; dt < 4; ++dt) {
        unsigned int t2[2];
        t2[0] = cvtpk(oacc[dt][0] * inv, oacc[dt][1] * inv);
        t2[1] = cvtpk(oacc[dt][2] * inv, oacc[dt][3] * inv);
        __builtin_memcpy(op + dt * 16, t2, 8);
    }
}

// ---------------------------------------------------------------- launch
extern "C" void kernel_launch(void* const* d_in, const int* in_sizes, int n_in,
                              void* d_out, int out_size, void* d_ws, size_t ws_size,
                              hipStream_t stream) {
    const float* x      = (const float*)d_in[0];
    const float* pos    = (const float*)d_in[1];
    const float* qkv_w  = (const float*)d_in[2];
    const float* qkv_b  = (const float*)d_in[3];
    const float* proj_w = (const float*)d_in[4];
    const float* proj_b = (const float*)d_in[5];
    const float* mlp_w1 = (const float*)d_in[6];
    const float* mlp_b1 = (const float*)d_in[7];
    const float* mlp_w2 = (const float*)d_in[8];
    const float* mlp_b2 = (const float*)d_in[9];
    const float* ln1_g  = (const float*)d_in[10];
    const float* ln1_b  = (const float*)d_in[11];
    const float* ln2_g  = (const float*)d_in[12];
    const float* ln2_b  = (const float*)d_in[13];

    char* p = (char*)d_ws;
    size_t off = 0;
    auto alloc = [&](size_t bytes) {
        char* r = p + off;
        off = (off + bytes + 255) & ~(size_t)255;
        return r;
    };
    bf16* WT1 = (bf16*)alloc((size_t)1152 * 384 * 2);
    bf16* WT2 = (bf16*)alloc((size_t)384 * 384 * 2);
    bf16* WT3 = (bf16*)alloc((size_t)384 * 768 * 2);
    bf16* WT4 = (bf16*)alloc((size_t)768 * 384 * 2);
    bf16* xn  = (bf16*)alloc((size_t)NTOK * DIMD * 2);
    bf16* xn2 = (bf16*)alloc((size_t)NTOK * DIMD * 2);
    bf16* qb  = (bf16*)alloc((size_t)NTOK * DIMD * 2);
    bf16* kb  = (bf16*)alloc((size_t)NTOK * DIMD * 2);
    bf16* vTb = (bf16*)alloc((size_t)NTOK * DIMD * 2);
    bf16* ao  = (bf16*)alloc((size_t)NTOK * DIMD * 2);
    float* x1 = (float*)alloc((size_t)NTOK * DIMD * 4);
    bf16* hh  = (bf16*)alloc((size_t)NTOK * MLPH * 2);
    bf16* dtab = (bf16*)alloc((size_t)NBATCH * SEQ * SEQ * 2);  // 32 MiB (DP)
    if (off > ws_size) return;  // workspace too small; cannot run

    // prep: 4 weight transposes + dist table + ln1, one launch
    prep_k<<<1152 + 512 + 2048, 256, 0, stream>>>(
        qkv_w, proj_w, mlp_w1, mlp_w2, WT1, WT2, WT3, WT4,
        pos, dtab, x, ln1_g, ln1_b, xn);

    // qkv GEMM -> q(pre-scaled), k, vT(transposed+permuted); grid 9x64 -> 576
    gemm128_k<0, 9, 12><<<576, 256, 0, stream>>>(
        xn, WT1, qkv_b, qb, kb, vTb, 384, 1152);
    attn_k<<<NBATCH * NHEADS * (SEQ / 64), 256, 0, stream>>>(qb, kb, vTb, dtab, ao);
    // proj + residual -> x1 (f32); grid 6x128 -> 768; KCN = 384/64 = 6
    gemm_k<6, 6><<<768, 256, 0, stream>>>(
        ao, WT2, proj_b, x, x1, 384, 384);
    ln_k<<<NTOK / 4, 256, 0, stream>>>(x1, ln2_g, ln2_b, xn2);
    // mlp1 + gelu -> hh; grid 6x64 -> 384; KCN = 384/32 = 12
    gemm128_k<2, 6, 12><<<384, 256, 0, stream>>>(
        xn2, WT3, mlp_b1, hh, nullptr, nullptr, 384, 768);
    // mlp2 + residual -> out (f32); grid 6x128 -> 768; KCN = 768/64 = 12
    gemm_k<6, 12><<<768, 256, 0, stream>>>(
        hh, WT4, mlp_b2, x1, (float*)d_out, 768, 384);
}